// Round 13
// baseline (279.717 us; speedup 1.0000x reference)
//
#include <hip/hip_runtime.h>

// ---------------- constants ----------------
#define BATCH   131072
#define INDIM   1024
#define BM      64
#define BDIM    512
#define NBLK    (BATCH / BM)          // 2048

// ---- LDS layout (bytes), phase-multiplexed ----
#define WT_OFF   0                    // G1 w-tile [384][128] bf16 (98304), wave-private strips
#define XT0_OFF  98304                // x-tile buf0 [64][128] bf16 (16384)
#define XT1_OFF  114688               // buf1 -> 131072
#define Z1_OFF   0                    // z1 [64][392] bf16 (50176)
#define W2T0_OFF 50176                // w2 strip buf0 [128][32] (8192)
#define W2T1_OFF 58368                // buf1 -> 66560
#define FZ_OFF   0                    // fused [64][264] bf16 (33792)
#define RP_OFF   33792                // rowpart [64][8] f32 (2048)
#define W3T0_OFF 42240                // w3 tile buf0 [384][32] (24576) -> 66816
#define W3T1_OFF 66816                // buf1 -> 91392
#define CB_OFF   131072
#define B1S_OFF  (CB_OFF)             // 384 f32
#define B2S_OFF  (CB_OFF + 1536)      // 128 f32
#define B3S_OFF  (CB_OFF + 2048)      // 384 f32
#define W4S_OFF  (CB_OFF + 3584)      // 384 f32
#define MKS_OFF  (CB_OFF + 5120)      // mk bf16 [32][136] (8704)
#define SMEM_BYTES (CB_OFF + 13824)   // 144896 -> 1 block/CU (proven equivalent to 2)

typedef unsigned short u16;
typedef u16    u16x8  __attribute__((ext_vector_type(8)));
typedef u16    u16x4  __attribute__((ext_vector_type(4)));
typedef __bf16 bf16x8 __attribute__((ext_vector_type(8)));
typedef __bf16 bf16x4 __attribute__((ext_vector_type(4)));
typedef float  f32x4  __attribute__((ext_vector_type(4)));

__device__ __forceinline__ u16 f2bf(float f) {
  unsigned u = __float_as_uint(f);
  u += 0x7FFFu + ((u >> 16) & 1u);    // RNE
  return (u16)(u >> 16);
}

// tanh-form GELU via sigmoid (max abs err ~3e-4, budget 1e-2)
__device__ __forceinline__ float gelu_fast(float v) {
  float t = v * v;
  float u = v * fmaf(t, 0.0356774081f, 0.7978845608f);
  float e = __builtin_amdgcn_exp2f(u * -2.885390082f);
  return v * __builtin_amdgcn_rcpf(1.0f + e);
}

__device__ __forceinline__ f32x4 mfma16(u16x8 a, u16x8 b, f32x4 c) {
  return __builtin_amdgcn_mfma_f32_16x16x32_bf16(
      __builtin_bit_cast(bf16x8, a), __builtin_bit_cast(bf16x8, b), c, 0, 0, 0);
}

__device__ __forceinline__ u16x8 cvt8(float4 a, float4 b) {
  bf16x8 r;
  r[0]=(__bf16)a.x; r[1]=(__bf16)a.y; r[2]=(__bf16)a.z; r[3]=(__bf16)a.w;
  r[4]=(__bf16)b.x; r[5]=(__bf16)b.y; r[6]=(__bf16)b.z; r[7]=(__bf16)b.w;
  return __builtin_bit_cast(u16x8, r);
}
__device__ __forceinline__ u16x4 cvt4(float4 a) {
  bf16x4 r;
  r[0]=(__bf16)a.x; r[1]=(__bf16)a.y; r[2]=(__bf16)a.z; r[3]=(__bf16)a.w;
  return __builtin_bit_cast(u16x4, r);
}

typedef __attribute__((address_space(3))) unsigned int       lds_u32;
typedef __attribute__((address_space(1))) const unsigned int glb_u32;
__device__ __forceinline__ void gload16(const void* g, void* l) {
  __builtin_amdgcn_global_load_lds((glb_u32*)g, (lds_u32*)l, 16, 0, 0);
}

#define FENCE_SCHED __builtin_amdgcn_sched_barrier(0)
// SOFT waits: memory ops ordered (clobber); register-only MFMA schedules freely
#define SOFT_LGKM0 asm volatile("s_waitcnt lgkmcnt(0)" ::: "memory")
#define SOFT_VMN(N) asm volatile("s_waitcnt vmcnt(" #N ")" ::: "memory")
// barrier with lgkm-only drain: DMA prefetches stay in flight across phases
#define BARRIER_LGKM do { \
  asm volatile("s_waitcnt lgkmcnt(0)" ::: "memory"); \
  __builtin_amdgcn_s_barrier(); FENCE_SCHED; } while (0)

// ---------------- prep: bf16-cast + transpose into chunk-swizzled K-tiles ----------------
// w1s: 8 tiles [384 r][128 k]; 16B chunk cp holds source chunk (cp&8)|((cp^(r&7))&7)
// w2s: 12 tiles [128 r][32 k], cp^((r>>1)&3)
// w3s:  8 tiles [384 r][32 k], cp^((r>>1)&3)
__global__ void prep_kernel(const float* __restrict__ w1, const float* __restrict__ w2,
                            const float* __restrict__ w3, u16* __restrict__ w1s,
                            u16* __restrict__ w2s, u16* __restrict__ w3s) {
  int i = blockIdx.x * 256 + threadIdx.x;
  if (i < 393216) {
    int t = i / 49152, p = i % 49152;
    int r = p >> 7, q = p & 127, cp = q >> 3, o = q & 7;
    int cs = (cp & 8) | ((cp ^ (r & 7)) & 7);
    int k = t * 128 + cs * 8 + o;
    w1s[i] = f2bf(w1[k * 384 + r]);
  } else if (i < 442368) {
    int j = i - 393216;
    int t = j / 4096, p = j % 4096;
    int r = p >> 5, q = p & 31, cp = q >> 3, o = q & 7;
    int k = t * 32 + ((cp ^ ((r >> 1) & 3)) << 3) + o;
    w2s[j] = f2bf(w2[k * 128 + r]);
  } else if (i < 540672) {
    int j = i - 442368;
    int t = j / 12288, p = j % 12288;
    int r = p >> 5, q = p & 31, cp = q >> 3, o = q & 7;
    int k = t * 32 + ((cp ^ ((r >> 1) & 3)) << 3) + o;
    w3s[j] = f2bf(w3[k * 384 + r]);
  }
}

// ---------------- fused forward: 8 waves x (64x48); G1 BK=128, 8 phases ----------------
__global__ __launch_bounds__(BDIM, 2) void fused_kernel(
    const float* __restrict__ x,  const u16* __restrict__ w1s,
    const float* __restrict__ b1, const u16* __restrict__ w2s,
    const float* __restrict__ b2, const float* __restrict__ mkw,
    const float* __restrict__ mvw, const u16* __restrict__ w3s,
    const float* __restrict__ b3, const float* __restrict__ w4,
    const float* __restrict__ b4, float* __restrict__ out) {
  extern __shared__ char smem[];
  u16*   z1  = (u16*)(smem + Z1_OFF);
  u16*   fz  = (u16*)(smem + FZ_OFF);
  float* b1s = (float*)(smem + B1S_OFF);
  float* b2s = (float*)(smem + B2S_OFF);
  float* b3s = (float*)(smem + B3S_OFF);
  float* w4s = (float*)(smem + W4S_OFF);
  u16*   mks = (u16*)(smem + MKS_OFF);
  float* rowpart = (float*)(smem + RP_OFF);

  const int tid  = threadIdx.x;
  const int lane = tid & 63;
  const int wid  = tid >> 6;          // 0..7: wave owns 48 w-cols (G1/G3), 16 (G2)
  const int l15  = lane & 15;
  const int g    = lane >> 4;         // 0..3
  const int swz4 = (l15 >> 1) & 3;
  const int row0 = blockIdx.x * BM;
  const int wrow = wid * 48;
  const int wstrip = wid * 6144;      // u16 offset of 48-row strip in [384][128]

  // ---------- prologue ----------
  {   // G1 strip(0) DMA (wave-private, 12 KB)
    const u16* ws = w1s + wstrip + lane * 8;
    u16* wd = (u16*)(smem + WT_OFF) + wstrip;
    #pragma unroll
    for (int i = 0; i < 12; ++i) gload16(ws + i * 512, wd + i * 512);
  }
  FENCE_SCHED;
  // x: thread covers row=tid>>3, 16 cols (xq=tid&7): 4 float4 per 128-col tile
  const int xrow = tid >> 3, xq = tid & 7;
  const float* xp = x + (long)(row0 + xrow) * INDIM + xq * 16;
  const int c0 = 2 * xq, c1 = 2 * xq + 1;
  const int s0 = ((c0 & 8) | ((c0 ^ (xrow & 7)) & 7)) * 8;   // swizzled store chunks
  const int s1 = ((c1 & 8) | ((c1 ^ (xrow & 7)) & 7)) * 8;
  float4 xa0 = *(const float4*)xp,        xa1 = *(const float4*)(xp + 4);
  float4 xb0 = *(const float4*)(xp + 8),  xb1 = *(const float4*)(xp + 12);

  if (tid < 384) b1s[tid] = b1[tid];
  if (tid < 128) b2s[tid] = b2[tid];
  if (tid < 384) b3s[tid] = b3[tid];
  if (tid < 384) w4s[tid] = w4[tid];
  {
    int r = tid >> 4, cc = (tid & 15) * 8;
    const float4* pm = (const float4*)(mkw + r * 128 + cc);
    *(u16x8*)(mks + r * 136 + cc) = cvt8(pm[0], pm[1]);
  }
  {   // publish xt[0] (implicit vmcnt drains prologue loads; prologue-only)
    u16* xb = (u16*)(smem + XT0_OFF) + xrow * 128;
    *(u16x8*)(xb + s0) = cvt8(xa0, xa1);
    *(u16x8*)(xb + s1) = cvt8(xb0, xb1);
  }
  {   // x(1)
    const float* p = xp + 128;
    xa0 = *(const float4*)p;       xa1 = *(const float4*)(p + 4);
    xb0 = *(const float4*)(p + 8); xb1 = *(const float4*)(p + 12);
  }
  BARRIER_LGKM;

  // =========== GEMM1: z1 = gelu(x@w1+b1) [64x384], K=1024, BK=128, 8 phases ===========
  f32x4 acc[4][3];
  #pragma unroll
  for (int m = 0; m < 4; ++m)
    #pragma unroll
    for (int n = 0; n < 3; ++n) acc[m][n] = (f32x4){0.f, 0.f, 0.f, 0.f};

  const u16* wtb = (const u16*)(smem + WT_OFF);
  for (int kt = 0; kt < 8; ++kt) {
    if (kt < 7) { SOFT_VMN(4); } else { SOFT_VMN(0); }   // strip(kt) landed; 4 xloads fly
    const u16* xtb = (const u16*)(smem + ((kt & 1) ? XT1_OFF : XT0_OFF));
    #pragma unroll
    for (int s = 0; s < 4; ++s) {                        // 4 k-slices of 32
      const int c = s * 4 + g;
      const int cs = ((c & 8) | ((c ^ (l15 & 7)) & 7)) * 8;
      u16x8 af[4], bfr[3];
      #pragma unroll
      for (int m = 0; m < 4; ++m) af[m] = *(const u16x8*)(xtb + (m * 16 + l15) * 128 + cs);
      #pragma unroll
      for (int n = 0; n < 3; ++n) bfr[n] = *(const u16x8*)(wtb + (wrow + n * 16 + l15) * 128 + cs);
      #pragma unroll
      for (int m = 0; m < 4; ++m)
        #pragma unroll
        for (int n = 0; n < 3; ++n) acc[m][n] = mfma16(bfr[n], af[m], acc[m][n]);
    }
    SOFT_LGKM0;                      // all 28 reads done -> strip/x-buf overwrite OK
    if (kt < 7) {
      {   // DMA W(kt+1) into my strip
        const u16* ws = w1s + (kt + 1) * 49152 + wstrip + lane * 8;
        u16* wd = (u16*)(smem + WT_OFF) + wstrip;
        #pragma unroll
        for (int i = 0; i < 12; ++i) gload16(ws + i * 512, wd + i * 512);
      }
      {   // publish xt[kt+1] (implicit vmcnt retires only the 4 x-loads)
        u16* xb = (u16*)(smem + ((kt & 1) ? XT0_OFF : XT1_OFF)) + xrow * 128;
        *(u16x8*)(xb + s0) = cvt8(xa0, xa1);
        *(u16x8*)(xb + s1) = cvt8(xb0, xb1);
      }
      if (kt < 6) {                  // stream x(kt+2)
        const float* p = xp + (kt + 2) * 128;
        xa0 = *(const float4*)p;       xa1 = *(const float4*)(p + 4);
        xb0 = *(const float4*)(p + 8); xb1 = *(const float4*)(p + 12);
      }
    }
    BARRIER_LGKM;
  }

  // G2 strips 0,1 DMA (wave-private, land under z1 epilogue)
  {
    const u16* s2 = w2s + wid * 512 + lane * 8;
    gload16(s2, (u16*)(smem + W2T0_OFF) + wid * 512);
    const u16* s2b = w2s + 4096 + wid * 512 + lane * 8;
    gload16(s2b, (u16*)(smem + W2T1_OFF) + wid * 512);
  }
  // z1 epilogue: b64 writes of 4 consecutive cols
  #pragma unroll
  for (int m = 0; m < 4; ++m) {
    #pragma unroll
    for (int n = 0; n < 3; ++n) {
      int col = wrow + n * 16 + g * 4;
      float4 bv = *(const float4*)(b1s + col);
      f32x4 a = acc[m][n];
      float4 gv = {gelu_fast(a[0] + bv.x), gelu_fast(a[1] + bv.y),
                   gelu_fast(a[2] + bv.z), gelu_fast(a[3] + bv.w)};
      *(u16x4*)(z1 + (m * 16 + l15) * 392 + col) = cvt4(gv);
    }
  }
  BARRIER_LGKM;                      // z1 visible

  // =========== GEMM2: z = gelu(z1@w2+b2) [64x128], K=384, BK=32, soft-paced ===========
  f32x4 acc2[4];
  #pragma unroll
  for (int m = 0; m < 4; ++m) acc2[m] = (f32x4){0.f, 0.f, 0.f, 0.f};
  for (int kt = 0; kt < 12; ++kt) {
    if (kt < 11) { SOFT_VMN(1); } else { SOFT_VMN(0); }
    const u16* wb = (const u16*)(smem + ((kt & 1) ? W2T1_OFF : W2T0_OFF));
    u16x8 a2f[4];
    #pragma unroll
    for (int m = 0; m < 4; ++m)
      a2f[m] = *(const u16x8*)(z1 + (m * 16 + l15) * 392 + kt * 32 + g * 8);
    u16x8 b2f = *(const u16x8*)(wb + (wid * 16 + l15) * 32 + (g ^ swz4) * 8);
    SOFT_LGKM0;
    if (kt < 10) {
      const u16* s2 = w2s + (kt + 2) * 4096 + wid * 512 + lane * 8;
      gload16(s2, (u16*)(smem + ((kt & 1) ? W2T1_OFF : W2T0_OFF)) + wid * 512);
    }
    #pragma unroll
    for (int m = 0; m < 4; ++m) acc2[m] = mfma16(b2f, a2f[m], acc2[m]);
  }
  BARRIER_LGKM;                      // z1/w2t dead -> fz & w3t regions usable

  // G3 strips 0,1 DMA early (covered by fz epilogue + logits + top2)
  {
    const u16* s3 = w3s + wid * 1536 + lane * 8;
    u16* d3 = (u16*)(smem + W3T0_OFF) + wid * 1536;
    gload16(s3, d3); gload16(s3 + 512, d3 + 512); gload16(s3 + 1024, d3 + 1024);
    const u16* s3b = w3s + 12288 + wid * 1536 + lane * 8;
    u16* d3b = (u16*)(smem + W3T1_OFF) + wid * 1536;
    gload16(s3b, d3b); gload16(s3b + 512, d3b + 512); gload16(s3b + 1024, d3b + 1024);
  }
  // fz epilogue (z part): b64 writes
  #pragma unroll
  for (int m = 0; m < 4; ++m) {
    int col = wid * 16 + g * 4;
    float4 bv = *(const float4*)(b2s + col);
    f32x4 a = acc2[m];
    float4 gv = {gelu_fast(a[0] + bv.x), gelu_fast(a[1] + bv.y),
                 gelu_fast(a[2] + bv.z), gelu_fast(a[3] + bv.w)};
    *(u16x4*)(fz + (m * 16 + l15) * 264 + col) = cvt4(gv);
  }
  BARRIER_LGKM;                      // fz(z) visible

  // =========== logits + in-register top-2 + mem blend (waves 0..3, rows wid*16+l15) ===========
  if (wid < 4) {
    const int wr = wid * 16 + l15;
    f32x4 accl[2] = {(f32x4){0,0,0,0}, (f32x4){0,0,0,0}};
    #pragma unroll
    for (int ks = 0; ks < 4; ++ks) {
      u16x8 afz = *(const u16x8*)(fz + wr * 264 + ks * 32 + g * 8);
      u16x8 k0  = *(const u16x8*)(mks + l15 * 136 + ks * 32 + g * 8);
      u16x8 k1  = *(const u16x8*)(mks + (16 + l15) * 136 + ks * 32 + g * 8);
      accl[0] = mfma16(k0, afz, accl[0]);   // D[slot][row]: lane=row, slot=n*16+g*4+j
      accl[1] = mfma16(k1, afz, accl[1]);
    }
    float m1 = -3.4e38f, m2 = -3.4e38f; int i1 = -1, i2 = -1;
    #pragma unroll
    for (int n = 0; n < 2; ++n)
      #pragma unroll
      for (int j = 0; j < 4; ++j) {
        float v = accl[n][j]; int idx = n * 16 + g * 4 + j;
        if (v > m1) { m2 = m1; i2 = i1; m1 = v; i1 = idx; }
        else if (v > m2) { m2 = v; i2 = idx; }
      }
    #pragma unroll
    for (int d = 16; d <= 32; d <<= 1) {   // merge across g-groups (same row)
      float om1 = __shfl_xor(m1, d); int oi1 = __shfl_xor(i1, d);
      float om2 = __shfl_xor(m2, d); int oi2 = __shfl_xor(i2, d);
      bool take = (om1 > m1) || (om1 == m1 && oi1 < i1);
      if (take) {
        float nm2; int ni2;
        if (m1 > om2 || (m1 == om2 && i1 < oi2)) { nm2 = m1; ni2 = i1; }
        else { nm2 = om2; ni2 = oi2; }
        m1 = om1; i1 = oi1; m2 = nm2; i2 = ni2;
      } else {
        if (om1 > m2 || (om1 == m2 && oi1 < i2)) { m2 = om1; i2 = oi1; }
      }
    }
    // 2-way softmax (tau folded into exponent); fast exp2/rcp
    float a1 = __builtin_amdgcn_rcpf(
        1.0f + __builtin_amdgcn_exp2f((m2 - m1) * (1.44269504f / 0.7f)));
    float a2 = 1.0f - a1;
    const float* v1 = mvw + i1 * 128 + g * 32;
    const float* v2 = mvw + i2 * 128 + g * 32;
    #pragma unroll
    for (int c = 0; c < 4; ++c) {
      float4 A0 = *(const float4*)(v1 + c * 8), A1 = *(const float4*)(v1 + c * 8 + 4);
      float4 B0 = *(const float4*)(v2 + c * 8), B1 = *(const float4*)(v2 + c * 8 + 4);
      float4 r0 = {a1*A0.x + a2*B0.x, a1*A0.y + a2*B0.y, a1*A0.z + a2*B0.z, a1*A0.w + a2*B0.w};
      float4 r1 = {a1*A1.x + a2*B1.x, a1*A1.y + a2*B1.y, a1*A1.z + a2*B1.z, a1*A1.w + a2*B1.w};
      *(u16x8*)(fz + wr * 264 + 128 + g * 32 + c * 8) = cvt8(r0, r1);
    }
  }
  BARRIER_LGKM;                      // mem visible

  // =========== GEMM3: h = gelu(fused@w3+b3) [64x384], K=256, BK=32, dbuf, soft-paced ======
  f32x4 acc3[4][3];
  #pragma unroll
  for (int m = 0; m < 4; ++m)
    #pragma unroll
    for (int n = 0; n < 3; ++n) acc3[m][n] = (f32x4){0.f, 0.f, 0.f, 0.f};
  for (int kt = 0; kt < 8; ++kt) {
    if (kt < 7) { SOFT_VMN(3); } else { SOFT_VMN(0); }   // buf(kt) landed; buf(kt+1) flies
    const u16* wb = (const u16*)(smem + ((kt & 1) ? W3T1_OFF : W3T0_OFF));
    u16x8 a3f[4], b3f[3];
    #pragma unroll
    for (int m = 0; m < 4; ++m)
      a3f[m] = *(const u16x8*)(fz + (m * 16 + l15) * 264 + kt * 32 + g * 8);
    #pragma unroll
    for (int n = 0; n < 3; ++n)
      b3f[n] = *(const u16x8*)(wb + (wrow + n * 16 + l15) * 32 + (g ^ swz4) * 8);
    SOFT_LGKM0;
    if (kt < 6) {
      const u16* s3 = w3s + (kt + 2) * 12288 + wid * 1536 + lane * 8;
      u16* d3 = (u16*)(smem + ((kt & 1) ? W3T1_OFF : W3T0_OFF)) + wid * 1536;
      gload16(s3, d3); gload16(s3 + 512, d3 + 512); gload16(s3 + 1024, d3 + 1024);
    }
    #pragma unroll
    for (int m = 0; m < 4; ++m)
      #pragma unroll
      for (int n = 0; n < 3; ++n) acc3[m][n] = mfma16(b3f[n], a3f[m], acc3[m][n]);
  }

  // epilogue: per-row dot with w4; lane holds 4 consecutive cols -> 2-step shuffle reduce
  #pragma unroll
  for (int m = 0; m < 4; ++m) {
    float s = 0.f;
    #pragma unroll
    for (int n = 0; n < 3; ++n) {
      int col = wrow + n * 16 + g * 4;
      float4 bv = *(const float4*)(b3s + col);
      float4 wv = *(const float4*)(w4s + col);
      f32x4 a = acc3[m][n];
      s += gelu_fast(a[0] + bv.x) * wv.x + gelu_fast(a[1] + bv.y) * wv.y +
           gelu_fast(a[2] + bv.z) * wv.z + gelu_fast(a[3] + bv.w) * wv.w;
    }
    s += __shfl_xor(s, 16);
    s += __shfl_xor(s, 32);
    if (lane < 16) rowpart[(m * 16 + l15) * 8 + wid] = s;
  }
  BARRIER_LGKM;
  if (tid < BM) {
    const float4* rp = (const float4*)(rowpart + tid * 8);
    float4 p0 = rp[0], p1 = rp[1];
    float lg = b4[0] + p0.x + p0.y + p0.z + p0.w + p1.x + p1.y + p1.z + p1.w;
    out[row0 + tid] = __builtin_amdgcn_rcpf(1.0f + __builtin_amdgcn_exp2f(-lg * 1.44269504f));
  }
}

// ---------------- launch ----------------
extern "C" void kernel_launch(void* const* d_in, const int* in_sizes, int n_in,
                              void* d_out, int out_size, void* d_ws, size_t ws_size,
                              hipStream_t stream) {
  const float* x  = (const float*)d_in[0];
  const float* w1 = (const float*)d_in[1];
  const float* b1 = (const float*)d_in[2];
  const float* w2 = (const float*)d_in[3];
  const float* b2 = (const float*)d_in[4];
  const float* mk = (const float*)d_in[5];
  const float* mv = (const float*)d_in[6];
  const float* w3 = (const float*)d_in[7];
  const float* b3 = (const float*)d_in[8];
  const float* w4 = (const float*)d_in[9];
  const float* b4 = (const float*)d_in[10];

  u16* w1s = (u16*)d_ws;            // 393216 u16 (8 swizzled [384][128] tiles)
  u16* w2s = w1s + 393216;          // 49152 (12 [128][32] tiles)
  u16* w3s = w1s + 442368;          // 98304 (8 [384][32] tiles)

  prep_kernel<<<2112, 256, 0, stream>>>(w1, w2, w3, w1s, w2s, w3s);

  (void)hipFuncSetAttribute(reinterpret_cast<const void*>(fused_kernel),
                            hipFuncAttributeMaxDynamicSharedMemorySize, SMEM_BYTES);
  fused_kernel<<<NBLK, BDIM, SMEM_BYTES, stream>>>(x, w1s, b1, w2s, b2, mk, mv, w3s,
                                                   b3, w4, b4, (float*)d_out);
}

// Round 14
// 230.351 us; speedup vs baseline: 1.2143x; 1.2143x over previous
//
#include <hip/hip_runtime.h>

// ---------------- constants ----------------
#define BATCH   131072
#define INDIM   1024
#define BM      128
#define BDIM    512
#define NBLK    (BATCH / BM)          // 1024

// ---- LDS layout (bytes), phase-multiplexed ----
#define WT0_OFF  0                    // G1 w-tile buf0 [384][64] bf16 (49152)
#define WT1_OFF  49152                // buf1 -> 98304
#define XT0_OFF  98304                // x-tile buf0 [128][64] bf16 (16384)
#define XT1_OFF  114688               // buf1 -> 131072
#define Z1_OFF   0                    // z1 [128][392] bf16 (100352)
#define W2T0_OFF 100352               // w2 tile buf0 [128][32] (8192)
#define W2T1_OFF 108544               // buf1 -> 116736
#define FZ_OFF   0                    // fused [128][264] bf16 (67584)
#define W3T0_OFF 67584                // w3 tile buf0 [384][32] (24576) -> 92160
#define W3T1_OFF 92160                // buf1 -> 116736
#define RP_OFF   116736               // rowpart [128][8] f32 (4096) -> 120832
#define CB_OFF   131072
#define B1S_OFF  (CB_OFF)             // 384 f32
#define B2S_OFF  (CB_OFF + 1536)      // 128 f32
#define B3S_OFF  (CB_OFF + 2048)      // 384 f32
#define W4S_OFF  (CB_OFF + 3584)      // 384 f32
#define MKS_OFF  (CB_OFF + 5120)      // mk bf16 [32][136] (8704)
#define SMEM_BYTES (CB_OFF + 13824)   // 144896 -> 1 block/CU (r12: 1 vs 2 equivalent)

typedef unsigned short u16;
typedef u16    u16x8  __attribute__((ext_vector_type(8)));
typedef u16    u16x4  __attribute__((ext_vector_type(4)));
typedef __bf16 bf16x8 __attribute__((ext_vector_type(8)));
typedef __bf16 bf16x4 __attribute__((ext_vector_type(4)));
typedef float  f32x4  __attribute__((ext_vector_type(4)));

__device__ __forceinline__ u16 f2bf(float f) {
  unsigned u = __float_as_uint(f);
  u += 0x7FFFu + ((u >> 16) & 1u);    // RNE
  return (u16)(u >> 16);
}

// tanh-form GELU via sigmoid (max abs err ~3e-4, budget 1e-2)
__device__ __forceinline__ float gelu_fast(float v) {
  float t = v * v;
  float u = v * fmaf(t, 0.0356774081f, 0.7978845608f);
  float e = __builtin_amdgcn_exp2f(u * -2.885390082f);
  return v * __builtin_amdgcn_rcpf(1.0f + e);
}

__device__ __forceinline__ f32x4 mfma16(u16x8 a, u16x8 b, f32x4 c) {
  return __builtin_amdgcn_mfma_f32_16x16x32_bf16(
      __builtin_bit_cast(bf16x8, a), __builtin_bit_cast(bf16x8, b), c, 0, 0, 0);
}

__device__ __forceinline__ u16x8 cvt8(float4 a, float4 b) {
  bf16x8 r;
  r[0]=(__bf16)a.x; r[1]=(__bf16)a.y; r[2]=(__bf16)a.z; r[3]=(__bf16)a.w;
  r[4]=(__bf16)b.x; r[5]=(__bf16)b.y; r[6]=(__bf16)b.z; r[7]=(__bf16)b.w;
  return __builtin_bit_cast(u16x8, r);
}
__device__ __forceinline__ u16x4 cvt4(float4 a) {
  bf16x4 r;
  r[0]=(__bf16)a.x; r[1]=(__bf16)a.y; r[2]=(__bf16)a.z; r[3]=(__bf16)a.w;
  return __builtin_bit_cast(u16x4, r);
}

typedef __attribute__((address_space(3))) unsigned int       lds_u32;
typedef __attribute__((address_space(1))) const unsigned int glb_u32;
__device__ __forceinline__ void gload16(const void* g, void* l) {
  __builtin_amdgcn_global_load_lds((glb_u32*)g, (lds_u32*)l, 16, 0, 0);
}

#define FENCE_SCHED __builtin_amdgcn_sched_barrier(0)
// SOFT waits: memory ops ordered (clobber); register-only MFMA schedules freely
#define SOFT_LGKM0 asm volatile("s_waitcnt lgkmcnt(0)" ::: "memory")
#define SOFT_VMN(N) asm volatile("s_waitcnt vmcnt(" #N ")" ::: "memory")
// barrier with lgkm-only drain: DMA prefetches stay in flight across phases
#define BARRIER_LGKM do { \
  asm volatile("s_waitcnt lgkmcnt(0)" ::: "memory"); \
  __builtin_amdgcn_s_barrier(); FENCE_SCHED; } while (0)

// ---------------- prep: bf16-cast + transpose into chunk-swizzled K-tiles ----------------
// w1s: 16 tiles [384 r][64 k], 16B chunk cp holds source k-chunk cp^(r&7)
// w2s: 12 tiles [128 r][32 k], cp^((r>>1)&3)
// w3s:  8 tiles [384 r][32 k], cp^((r>>1)&3)
__global__ void prep_kernel(const float* __restrict__ w1, const float* __restrict__ w2,
                            const float* __restrict__ w3, u16* __restrict__ w1s,
                            u16* __restrict__ w2s, u16* __restrict__ w3s) {
  int i = blockIdx.x * 256 + threadIdx.x;
  if (i < 393216) {
    int t = i / 24576, p = i % 24576;
    int r = p >> 6, q = p & 63, cp = q >> 3, o = q & 7;
    int k = t * 64 + ((cp ^ (r & 7)) << 3) + o;
    w1s[i] = f2bf(w1[k * 384 + r]);
  } else if (i < 442368) {
    int j = i - 393216;
    int t = j / 4096, p = j % 4096;
    int r = p >> 5, q = p & 31, cp = q >> 3, o = q & 7;
    int k = t * 32 + ((cp ^ ((r >> 1) & 3)) << 3) + o;
    w2s[j] = f2bf(w2[k * 128 + r]);
  } else if (i < 540672) {
    int j = i - 442368;
    int t = j / 12288, p = j % 12288;
    int r = p >> 5, q = p & 31, cp = q >> 3, o = q & 7;
    int k = t * 32 + ((cp ^ ((r >> 1) & 3)) << 3) + o;
    w3s[j] = f2bf(w3[k * 384 + r]);
  }
}

// -------- fused forward: BM=128, 8 waves (2M x 4N), wave tile 64x96 in G1 --------
__global__ __launch_bounds__(BDIM, 2) void fused_kernel(
    const float* __restrict__ x,  const u16* __restrict__ w1s,
    const float* __restrict__ b1, const u16* __restrict__ w2s,
    const float* __restrict__ b2, const float* __restrict__ mkw,
    const float* __restrict__ mvw, const u16* __restrict__ w3s,
    const float* __restrict__ b3, const float* __restrict__ w4,
    const float* __restrict__ b4, float* __restrict__ out) {
  extern __shared__ char smem[];
  u16*   z1  = (u16*)(smem + Z1_OFF);
  u16*   fz  = (u16*)(smem + FZ_OFF);
  float* b1s = (float*)(smem + B1S_OFF);
  float* b2s = (float*)(smem + B2S_OFF);
  float* b3s = (float*)(smem + B3S_OFF);
  float* w4s = (float*)(smem + W4S_OFF);
  u16*   mks = (u16*)(smem + MKS_OFF);
  float* rowpart = (float*)(smem + RP_OFF);

  const int tid  = threadIdx.x;
  const int lane = tid & 63;
  const int wid  = tid >> 6;          // 0..7
  const int l15  = lane & 15;
  const int g    = lane >> 4;         // 0..3
  const int sw   = l15 & 7;           // G1 chunk swizzle
  const int swz4 = (l15 >> 1) & 3;    // G2/G3 chunk swizzle
  const int row0 = blockIdx.x * BM;
  const int waveM = wid >> 2;         // 0..1 (x-row half)
  const int waveN = wid & 3;          // 0..3 (w-col quarter)
  const int wrow1 = waveN * 96;       // G1 w-col base
  const int wrow3 = wid * 48;         // G3 w-col base
  const int wstrip = wid * 3072;      // 48-row DMA strip in [384][64] (u16)

  // ---------- prologue ----------
  {   // W(0)->WT0, W(1)->WT1 (6 gloads each, strip-per-wave)
    const u16* ws = w1s + wstrip + lane * 8;
    u16* wd0 = (u16*)(smem + WT0_OFF) + wstrip;
    #pragma unroll
    for (int i = 0; i < 6; ++i) gload16(ws + i * 512, wd0 + i * 512);
    const u16* ws1 = ws + 24576;
    u16* wd1 = (u16*)(smem + WT1_OFF) + wstrip;
    #pragma unroll
    for (int i = 0; i < 6; ++i) gload16(ws1 + i * 512, wd1 + i * 512);
  }
  FENCE_SCHED;
  // x: thread covers row=tid>>2 (0..127), 16 cols (xq=tid&3): 4 float4 per 64-col tile
  const int xrow = tid >> 2, xq = tid & 3;
  const float* xp = x + (long)(row0 + xrow) * INDIM + xq * 16;
  const int xdst0 = xrow * 64 + (((2 * xq)     ^ (xrow & 7)) << 3);
  const int xdst1 = xrow * 64 + (((2 * xq + 1) ^ (xrow & 7)) << 3);
  float4 xa0 = *(const float4*)xp,       xa1 = *(const float4*)(xp + 4);
  float4 xb0 = *(const float4*)(xp + 8), xb1 = *(const float4*)(xp + 12);

  if (tid < 384) b1s[tid] = b1[tid];
  if (tid < 128) b2s[tid] = b2[tid];
  if (tid < 384) b3s[tid] = b3[tid];
  if (tid < 384) w4s[tid] = w4[tid];
  {
    int r = tid >> 4, cc = (tid & 15) * 8;
    const float4* pm = (const float4*)(mkw + r * 128 + cc);
    *(u16x8*)(mks + r * 136 + cc) = cvt8(pm[0], pm[1]);
  }
  {   // publish xt[0] (implicit vmcnt drains prologue loads; prologue-only)
    u16* xb = (u16*)(smem + XT0_OFF);
    *(u16x8*)(xb + xdst0) = cvt8(xa0, xa1);
    *(u16x8*)(xb + xdst1) = cvt8(xb0, xb1);
  }
  {   // x(1)
    const float* p = xp + 64;
    xa0 = *(const float4*)p;       xa1 = *(const float4*)(p + 4);
    xb0 = *(const float4*)(p + 8); xb1 = *(const float4*)(p + 12);
  }
  BARRIER_LGKM;

  // ==== GEMM1: z1 = gelu(x@w1+b1) [128x384], K=1024, BK=64, 16 phases ====
  // No explicit vmcnt in the loop: x-publish's implicit wait retires W(kt+1)
  // (older in FIFO) + x(kt+1); W(kt+2) and x(kt+2) fly across the barrier.
  f32x4 acc[4][6];
  #pragma unroll
  for (int m = 0; m < 4; ++m)
    #pragma unroll
    for (int n = 0; n < 6; ++n) acc[m][n] = (f32x4){0.f, 0.f, 0.f, 0.f};

  for (int kt = 0; kt < 16; ++kt) {
    const u16* xtb = (const u16*)(smem + ((kt & 1) ? XT1_OFF : XT0_OFF));
    const u16* wtb = (const u16*)(smem + ((kt & 1) ? WT1_OFF : WT0_OFF));
    u16x8 af[4], bfr[6];
    const int c0 = (g ^ sw) * 8;
    #pragma unroll
    for (int m = 0; m < 4; ++m)
      af[m] = *(const u16x8*)(xtb + (waveM * 64 + m * 16 + l15) * 64 + c0);
    #pragma unroll
    for (int n = 0; n < 6; ++n)
      bfr[n] = *(const u16x8*)(wtb + (wrow1 + n * 16 + l15) * 64 + c0);
    #pragma unroll
    for (int m = 0; m < 4; ++m)
      #pragma unroll
      for (int n = 0; n < 6; ++n) acc[m][n] = mfma16(bfr[n], af[m], acc[m][n]);
    const int c1 = ((g + 4) ^ sw) * 8;
    #pragma unroll
    for (int m = 0; m < 4; ++m)
      af[m] = *(const u16x8*)(xtb + (waveM * 64 + m * 16 + l15) * 64 + c1);
    #pragma unroll
    for (int n = 0; n < 6; ++n)
      bfr[n] = *(const u16x8*)(wtb + (wrow1 + n * 16 + l15) * 64 + c1);
    SOFT_LGKM0;                        // all reads of tile kt done -> buffers reusable
    if (kt < 15) {
      // publish xt(kt+1); implicit vmcnt retires x(kt+1) (+ already-old W(kt+1))
      u16* xn = (u16*)(smem + ((kt & 1) ? XT0_OFF : XT1_OFF));
      *(u16x8*)(xn + xdst0) = cvt8(xa0, xa1);
      *(u16x8*)(xn + xdst1) = cvt8(xb0, xb1);
      if (kt < 14) {
        // DMA W(kt+2) into the buffer just freed (2-phase flight)
        const u16* ws = w1s + (kt + 2) * 24576 + wstrip + lane * 8;
        u16* wd = (u16*)(smem + ((kt & 1) ? WT1_OFF : WT0_OFF)) + wstrip;
        #pragma unroll
        for (int i = 0; i < 6; ++i) gload16(ws + i * 512, wd + i * 512);
        FENCE_SCHED;                   // keep W ahead of x in vmcnt FIFO
        const float* p = xp + (kt + 2) * 64;   // stream x(kt+2)
        xa0 = *(const float4*)p;       xa1 = *(const float4*)(p + 4);
        xb0 = *(const float4*)(p + 8); xb1 = *(const float4*)(p + 12);
      }
    }
    #pragma unroll
    for (int m = 0; m < 4; ++m)
      #pragma unroll
      for (int n = 0; n < 6; ++n) acc[m][n] = mfma16(bfr[n], af[m], acc[m][n]);
    if (kt < 15) BARRIER_LGKM;
  }
  BARRIER_LGKM;                        // staging dead -> z1 region usable

  // G2 tiles 0,1 DMA (wave-private 16-row strips; land under z1 epilogue)
  {
    const u16* s2 = w2s + wid * 512 + lane * 8;
    gload16(s2, (u16*)(smem + W2T0_OFF) + wid * 512);
    const u16* s2b = w2s + 4096 + wid * 512 + lane * 8;
    gload16(s2b, (u16*)(smem + W2T1_OFF) + wid * 512);
  }
  // z1 epilogue
  #pragma unroll
  for (int m = 0; m < 4; ++m) {
    #pragma unroll
    for (int n = 0; n < 6; ++n) {
      int col = wrow1 + n * 16 + g * 4;
      float4 bv = *(const float4*)(b1s + col);
      f32x4 a = acc[m][n];
      float4 gv = {gelu_fast(a[0] + bv.x), gelu_fast(a[1] + bv.y),
                   gelu_fast(a[2] + bv.z), gelu_fast(a[3] + bv.w)};
      *(u16x4*)(z1 + (waveM * 64 + m * 16 + l15) * 392 + col) = cvt4(gv);
    }
  }
  BARRIER_LGKM;                        // z1 visible

  // ==== GEMM2: z = gelu(z1@w2+b2) [128x128], K=384, BK=32, no barriers ====
  f32x4 acc2[8];
  #pragma unroll
  for (int m = 0; m < 8; ++m) acc2[m] = (f32x4){0.f, 0.f, 0.f, 0.f};
  for (int kt = 0; kt < 12; ++kt) {
    if (kt < 11) { SOFT_VMN(1); } else { SOFT_VMN(0); }
    const u16* wb = (const u16*)(smem + ((kt & 1) ? W2T1_OFF : W2T0_OFF));
    u16x8 a2f[8];
    #pragma unroll
    for (int m = 0; m < 8; ++m)
      a2f[m] = *(const u16x8*)(z1 + (m * 16 + l15) * 392 + kt * 32 + g * 8);
    u16x8 b2f = *(const u16x8*)(wb + (wid * 16 + l15) * 32 + (g ^ swz4) * 8);
    SOFT_LGKM0;
    if (kt < 10) {
      const u16* s2 = w2s + (kt + 2) * 4096 + wid * 512 + lane * 8;
      gload16(s2, (u16*)(smem + ((kt & 1) ? W2T1_OFF : W2T0_OFF)) + wid * 512);
    }
    #pragma unroll
    for (int m = 0; m < 8; ++m) acc2[m] = mfma16(b2f, a2f[m], acc2[m]);
  }
  BARRIER_LGKM;                        // z1/w2t dead -> fz & w3t regions usable

  // G3 tiles 0,1 DMA early (covered by fz epilogue + logits + top2)
  {
    const u16* s3 = w3s + wrow3 * 32 + lane * 8;        // wid*48 rows *32 = wid*1536
    u16* d30 = (u16*)(smem + W3T0_OFF) + wid * 1536;
    gload16(s3, d30); gload16(s3 + 512, d30 + 512); gload16(s3 + 1024, d30 + 1024);
    const u16* s3b = w3s + 12288 + wid * 1536 + lane * 8;
    u16* d31 = (u16*)(smem + W3T1_OFF) + wid * 1536;
    gload16(s3b, d31); gload16(s3b + 512, d31 + 512); gload16(s3b + 1024, d31 + 1024);
  }
  // fz epilogue (z part): cols wid*16 + g*4
  #pragma unroll
  for (int m = 0; m < 8; ++m) {
    int col = wid * 16 + g * 4;
    float4 bv = *(const float4*)(b2s + col);
    f32x4 a = acc2[m];
    float4 gv = {gelu_fast(a[0] + bv.x), gelu_fast(a[1] + bv.y),
                 gelu_fast(a[2] + bv.z), gelu_fast(a[3] + bv.w)};
    *(u16x4*)(fz + (m * 16 + l15) * 264 + col) = cvt4(gv);
  }
  BARRIER_LGKM;                        // fz(z) visible

  // ==== logits + in-register top-2 + mem blend (ALL 8 waves, rows wid*16+l15) ====
  {
    const int wr = wid * 16 + l15;
    f32x4 accl[2] = {(f32x4){0,0,0,0}, (f32x4){0,0,0,0}};
    #pragma unroll
    for (int ks = 0; ks < 4; ++ks) {
      u16x8 afz = *(const u16x8*)(fz + wr * 264 + ks * 32 + g * 8);
      u16x8 k0  = *(const u16x8*)(mks + l15 * 136 + ks * 32 + g * 8);
      u16x8 k1  = *(const u16x8*)(mks + (16 + l15) * 136 + ks * 32 + g * 8);
      accl[0] = mfma16(k0, afz, accl[0]);   // D[slot][row]: lane=row
      accl[1] = mfma16(k1, afz, accl[1]);
    }
    float m1 = -3.4e38f, m2 = -3.4e38f; int i1 = -1, i2 = -1;
    #pragma unroll
    for (int n = 0; n < 2; ++n)
      #pragma unroll
      for (int j = 0; j < 4; ++j) {
        float v = accl[n][j]; int idx = n * 16 + g * 4 + j;
        if (v > m1) { m2 = m1; i2 = i1; m1 = v; i1 = idx; }
        else if (v > m2) { m2 = v; i2 = idx; }
      }
    #pragma unroll
    for (int d = 16; d <= 32; d <<= 1) {   // merge across g-groups (same row)
      float om1 = __shfl_xor(m1, d); int oi1 = __shfl_xor(i1, d);
      float om2 = __shfl_xor(m2, d); int oi2 = __shfl_xor(i2, d);
      bool take = (om1 > m1) || (om1 == m1 && oi1 < i1);
      if (take) {
        float nm2; int ni2;
        if (m1 > om2 || (m1 == om2 && i1 < oi2)) { nm2 = m1; ni2 = i1; }
        else { nm2 = om2; ni2 = oi2; }
        m1 = om1; i1 = oi1; m2 = nm2; i2 = ni2;
      } else {
        if (om1 > m2 || (om1 == m2 && oi1 < i2)) { m2 = om1; i2 = oi1; }
      }
    }
    float a1 = __builtin_amdgcn_rcpf(
        1.0f + __builtin_amdgcn_exp2f((m2 - m1) * (1.44269504f / 0.7f)));
    float a2 = 1.0f - a1;
    const float* v1 = mvw + i1 * 128 + g * 32;
    const float* v2 = mvw + i2 * 128 + g * 32;
    #pragma unroll
    for (int c = 0; c < 4; ++c) {
      float4 A0 = *(const float4*)(v1 + c * 8), A1 = *(const float4*)(v1 + c * 8 + 4);
      float4 B0 = *(const float4*)(v2 + c * 8), B1 = *(const float4*)(v2 + c * 8 + 4);
      float4 r0 = {a1*A0.x + a2*B0.x, a1*A0.y + a2*B0.y, a1*A0.z + a2*B0.z, a1*A0.w + a2*B0.w};
      float4 r1 = {a1*A1.x + a2*B1.x, a1*A1.y + a2*B1.y, a1*A1.z + a2*B1.z, a1*A1.w + a2*B1.w};
      *(u16x8*)(fz + wr * 264 + 128 + g * 32 + c * 8) = cvt8(r0, r1);
    }
  }
  BARRIER_LGKM;                        // mem visible

  // ==== GEMM3: h = gelu(fused@w3+b3) [128x384], K=256, BK=32, dbuf, no barriers ====
  f32x4 acc3[8][3];
  #pragma unroll
  for (int m = 0; m < 8; ++m)
    #pragma unroll
    for (int n = 0; n < 3; ++n) acc3[m][n] = (f32x4){0.f, 0.f, 0.f, 0.f};
  for (int kt = 0; kt < 8; ++kt) {
    if (kt < 7) { SOFT_VMN(3); } else { SOFT_VMN(0); }
    const u16* wb = (const u16*)(smem + ((kt & 1) ? W3T1_OFF : W3T0_OFF));
    u16x8 a3f[8], b3f[3];
    #pragma unroll
    for (int m = 0; m < 8; ++m)
      a3f[m] = *(const u16x8*)(fz + (m * 16 + l15) * 264 + kt * 32 + g * 8);
    #pragma unroll
    for (int n = 0; n < 3; ++n)
      b3f[n] = *(const u16x8*)(wb + (wrow3 + n * 16 + l15) * 32 + (g ^ swz4) * 8);
    SOFT_LGKM0;
    if (kt < 6) {
      const u16* s3 = w3s + (kt + 2) * 12288 + wid * 1536 + lane * 8;
      u16* d3 = (u16*)(smem + ((kt & 1) ? W3T1_OFF : W3T0_OFF)) + wid * 1536;
      gload16(s3, d3); gload16(s3 + 512, d3 + 512); gload16(s3 + 1024, d3 + 1024);
    }
    #pragma unroll
    for (int m = 0; m < 8; ++m)
      #pragma unroll
      for (int n = 0; n < 3; ++n) acc3[m][n] = mfma16(b3f[n], a3f[m], acc3[m][n]);
  }

  // epilogue: per-row dot with w4; 2-step shuffle reduce; rowpart disjoint from fz
  #pragma unroll
  for (int m = 0; m < 8; ++m) {
    float s = 0.f;
    #pragma unroll
    for (int n = 0; n < 3; ++n) {
      int col = wrow3 + n * 16 + g * 4;
      float4 bv = *(const float4*)(b3s + col);
      float4 wv = *(const float4*)(w4s + col);
      f32x4 a = acc3[m][n];
      s += gelu_fast(a[0] + bv.x) * wv.x + gelu_fast(a[1] + bv.y) * wv.y +
           gelu_fast(a[2] + bv.z) * wv.z + gelu_fast(a[3] + bv.w) * wv.w;
    }
    s += __shfl_xor(s, 16);
    s += __shfl_xor(s, 32);
    if (lane < 16) rowpart[(m * 16 + l15) * 8 + wid] = s;
  }
  BARRIER_LGKM;
  if (tid < BM) {
    const float4* rp = (const float4*)(rowpart + tid * 8);
    float4 p0 = rp[0], p1 = rp[1];
    float lg = b4[0] + p0.x + p0.y + p0.z + p0.w + p1.x + p1.y + p1.z + p1.w;
    out[row0 + tid] = __builtin_amdgcn_rcpf(1.0f + __builtin_amdgcn_exp2f(-lg * 1.44269504f));
  }
}

// ---------------- launch ----------------
extern "C" void kernel_launch(void* const* d_in, const int* in_sizes, int n_in,
                              void* d_out, int out_size, void* d_ws, size_t ws_size,
                              hipStream_t stream) {
  const float* x  = (const float*)d_in[0];
  const float* w1 = (const float*)d_in[1];
  const float* b1 = (const float*)d_in[2];
  const float* w2 = (const float*)d_in[3];
  const float* b2 = (const float*)d_in[4];
  const float* mk = (const float*)d_in[5];
  const float* mv = (const float*)d_in[6];
  const float* w3 = (const float*)d_in[7];
  const float* b3 = (const float*)d_in[8];
  const float* w4 = (const float*)d_in[9];
  const float* b4 = (const float*)d_in[10];

  u16* w1s = (u16*)d_ws;            // 393216 u16 (16 swizzled [384][64] tiles)
  u16* w2s = w1s + 393216;          // 49152 (12 [128][32] tiles)
  u16* w3s = w1s + 442368;          // 98304 (8 [384][32] tiles)

  prep_kernel<<<2112, 256, 0, stream>>>(w1, w2, w3, w1s, w2s, w3s);

  (void)hipFuncSetAttribute(reinterpret_cast<const void*>(fused_kernel),
                            hipFuncAttributeMaxDynamicSharedMemorySize, SMEM_BYTES);
  fused_kernel<<<NBLK, BDIM, SMEM_BYTES, stream>>>(x, w1s, b1, w2s, b2, mk, mv, w3s,
                                                   b3, w4, b4, (float*)d_out);
}